// Round 1
// baseline (2399.976 us; speedup 1.0000x reference)
//
#include <hip/hip_runtime.h>
#include <stdint.h>

typedef short bf16x8 __attribute__((ext_vector_type(8)));
typedef float f32x4 __attribute__((ext_vector_type(4)));
typedef unsigned long long u64;
typedef unsigned short u16;

// Problem constants
// B=16, N=1024, T=6, V=32000, D=128, F=64, H=4, LC=400

__device__ inline u16 f2b(float f) {
    unsigned u = __float_as_uint(f);
    u += 0x7fffu + ((u >> 16) & 1u);
    return (u16)(u >> 16);
}

__device__ inline float wred_sum(float v) {
    #pragma unroll
    for (int m = 32; m >= 1; m >>= 1) v += __shfl_xor(v, m, 64);
    return v;
}
__device__ inline float wred_max(float v) {
    #pragma unroll
    for (int m = 32; m >= 1; m >>= 1) v = fmaxf(v, __shfl_xor(v, m, 64));
    return v;
}

// ---------------------------------------------------------------------------
// K0: adjacency -> bitmask [B*N][16] u64, with diagonal fix (i>=start -> 1)
__global__ __launch_bounds__(256) void k_mask(const float* __restrict__ adj,
                                              const int* __restrict__ kb,
                                              const int* __restrict__ cv,
                                              u64* __restrict__ mask) {
    int tid = threadIdx.x;
    int w = tid >> 6, l = tid & 63;
    int row = blockIdx.x * 4 + w;            // b*1024 + i
    int b = row >> 10, i = row & 1023;
    int start = kb[b] + cv[b];
    const float* arow = adj + ((size_t)row << 10);
    u64* mrow = mask + ((size_t)row << 4);
    #pragma unroll
    for (int wd = 0; wd < 16; ++wd) {
        int j = (wd << 6) | l;
        bool p = arow[j] > 0.0f;
        if (j == i && i >= start) p = true;
        u64 bal = __ballot(p);
        if (l == 0) mrow[wd] = bal;
    }
}

// ---------------------------------------------------------------------------
// K1: x0 = sum_t emb[story] + (valid ? dh : 0), written as bf16 [B*N][128]
__global__ __launch_bounds__(128) void k_x0(const int* __restrict__ story,
                                            const int* __restrict__ kb,
                                            const int* __restrict__ cv,
                                            const float* __restrict__ dh,
                                            const float* __restrict__ emb,
                                            u16* __restrict__ x0) {
    int bn = blockIdx.x;
    int b = bn >> 10, n = bn & 1023;
    int d = threadIdx.x;
    const int* st = story + (size_t)bn * 6;
    float s = 0.0f;
    #pragma unroll
    for (int t = 0; t < 6; ++t) {
        int tok = st[t];
        s += emb[((size_t)tok << 7) + d];
    }
    int off = n - (kb[b] - 1);
    if (off >= 0 && off < cv[b]) s += dh[((size_t)b * 400 + off) * 128 + d];
    x0[((size_t)bn << 7) + d] = f2b(s);
}

// ---------------------------------------------------------------------------
// K2: pack W [H][K][64] fp32 -> MFMA B-fragment layout bf16
//     Bpack[((kt*16+ct)*64 + lane)*8 + j] = W[col>>6][kt*32+(lane>>4)*8+j][col&63]
//     with col = ct*16 + (lane&15)
__global__ __launch_bounds__(256) void k_prepW(const float* __restrict__ W,
                                               u16* __restrict__ Bpack, int K) {
    int id = blockIdx.x * 256 + threadIdx.x;
    if (id >= K * 32) return;
    int lane = id & 63;
    int ctk = id >> 6;
    int ct = ctk & 15, kt = ctk >> 4;
    int col = (ct << 4) | (lane & 15);
    int h = col >> 6, f = col & 63;
    int kbase = (kt << 5) + ((lane >> 4) << 3);
    u16* o = Bpack + (size_t)id * 8;
    #pragma unroll
    for (int j = 0; j < 8; ++j) {
        o[j] = f2b(W[((size_t)h * K + kbase + j) * 64 + f]);
    }
}

// ---------------------------------------------------------------------------
// K3: Wh[16384][256] = A[16384][K] (bf16) @ Wcat[K][256] via 16x16x32 MFMA
template <int KT>
__global__ __launch_bounds__(256) void k_gemm(const u16* __restrict__ A,
                                              const u16* __restrict__ Bp,
                                              float* __restrict__ Wh) {
    constexpr int K = KT * 32;
    int tid = threadIdx.x;
    int w = tid >> 6, l = tid & 63;
    int rt = blockIdx.x * 4 + w;
    int m0 = rt << 4;
    const bf16x8* Av = (const bf16x8*)A;
    const bf16x8* Bv = (const bf16x8*)Bp;
    int arow = m0 + (l & 15);
    bf16x8 af[KT];
    #pragma unroll
    for (int kt = 0; kt < KT; ++kt)
        af[kt] = Av[(((size_t)arow * K) + (kt << 5) + ((l >> 4) << 3)) >> 3];
    int ro = (l >> 4) << 2;
    int co = l & 15;
    for (int ct = 0; ct < 16; ++ct) {
        f32x4 acc = {0.f, 0.f, 0.f, 0.f};
        #pragma unroll
        for (int kt = 0; kt < KT; ++kt)
            acc = __builtin_amdgcn_mfma_f32_16x16x32_bf16(af[kt], Bv[(kt * 16 + ct) * 64 + l], acc, 0, 0, 0);
        int col = (ct << 4) + co;
        #pragma unroll
        for (int j = 0; j < 4; ++j)
            Wh[(size_t)(m0 + ro + j) * 256 + col] = acc[j];
    }
}

// ---------------------------------------------------------------------------
// K4: f1[b,h,n] = Wh[b,n,h*64+f] . a[h][f],  f2 with a[h][64+f]
__global__ __launch_bounds__(256) void k_f12(const float* __restrict__ Wh,
                                             const float* __restrict__ a,
                                             float* __restrict__ f1,
                                             float* __restrict__ f2) {
    int bn = blockIdx.x;
    int t = threadIdx.x;
    int h = t >> 6, f = t & 63;
    float v = Wh[((size_t)bn << 8) + t];
    float p1 = v * a[h * 128 + f];
    float p2 = v * a[h * 128 + 64 + f];
    p1 = wred_sum(p1);
    p2 = wred_sum(p2);
    if (f == 0) {
        int b = bn >> 10, n = bn & 1023;
        int o = ((b * 4 + h) << 10) + n;
        f1[o] = p1;
        f2[o] = p2;
    }
}

// ---------------------------------------------------------------------------
// K5: sparse masked softmax + PV.  MODE 0: concat layer (elu -> bf16 x).
//     MODE 1: final layer (fp32 per-head out3).
template <int MODE>
__global__ __launch_bounds__(256) void k_pv(const u64* __restrict__ mask,
                                            const float* __restrict__ f1g,
                                            const float* __restrict__ f2g,
                                            const float* __restrict__ Wh,
                                            u16* __restrict__ xout,
                                            float* __restrict__ out3) {
    __shared__ float f2s[1024];
    __shared__ float pbuf[4][1024];
    int tid = threadIdx.x;
    int w = tid >> 6, l = tid & 63;
    int bh = blockIdx.x >> 3, chunk = blockIdx.x & 7;
    int b = bh >> 2, h = bh & 3;
    for (int idx = tid; idx < 1024; idx += 256) f2s[idx] = f2g[(bh << 10) + idx];
    __syncthreads();
    const float NEGINF = -3.0e38f;
    const float* Wb = Wh + ((size_t)(b << 10) << 8) + (h << 6) + l;  // Wh[b*1024 + j][h*64+l]
    for (int r = 0; r < 32; ++r) {
        int i = (chunk << 7) + (w << 5) + r;
        const u64* mrow = mask + (((size_t)(b << 10) + i) << 4);
        float f1i = f1g[(bh << 10) + i];
        // pass 1: neighbor max of f2, degree
        float mloc = NEGINF;
        int deg = 0;
        #pragma unroll
        for (int wd = 0; wd < 16; ++wd) {
            u64 word = mrow[wd];
            deg += __popcll(word);
            if ((word >> l) & 1) mloc = fmaxf(mloc, f2s[(wd << 6) | l]);
        }
        float m = wred_max(mloc);
        float acc;
        if (deg == 0) {
            // softmax over all-NEG_INF row = uniform 1/N -> column mean of Wh
            acc = 0.0f;
            for (int j = 0; j < 1024; ++j) acc += Wb[(size_t)j << 8];
            acc *= (1.0f / 1024.0f);
        } else {
            float emax = f1i + m;
            emax = emax > 0.0f ? emax : 0.2f * emax;  // leakyrelu monotonic
            // pass 2: p = exp(e - emax), row sum
            float ss = 0.0f;
            #pragma unroll
            for (int wd = 0; wd < 16; ++wd) {
                u64 word = mrow[wd];
                float e = f1i + f2s[(wd << 6) | l];
                e = e > 0.0f ? e : 0.2f * e;
                float p = ((word >> l) & 1) ? __expf(e - emax) : 0.0f;
                pbuf[w][(wd << 6) | l] = p;
                ss += p;
            }
            float rinv = 1.0f / wred_sum(ss);
            // pass 3: PV over set bits, lane = output feature
            acc = 0.0f;
            for (int wd = 0; wd < 16; ++wd) {
                u64 word = mrow[wd];
                while (word) {
                    int t2 = __ffsll(word) - 1;
                    word &= word - 1;
                    int j = (wd << 6) + t2;
                    acc += pbuf[w][j] * Wb[(size_t)j << 8];
                }
            }
            acc *= rinv;
        }
        if (MODE == 0) {
            float e = acc > 0.0f ? acc : (__expf(acc) - 1.0f);  // elu
            xout[(((size_t)(b << 10) + i) << 8) + (h << 6) + l] = f2b(e);
        } else {
            out3[((((size_t)bh << 10) + i) << 6) + l] = acc;
        }
    }
}

// ---------------------------------------------------------------------------
// K6: final head-mean -> sigmoid -> dot(hidden) -> outputs
__global__ __launch_bounds__(64) void k_final(const float* __restrict__ out3,
                                              const float* __restrict__ hidden,
                                              float* __restrict__ dout) {
    int bn = blockIdx.x;
    int b = bn >> 10, n = bn & 1023;
    int f = threadIdx.x;
    float s = 0.0f;
    #pragma unroll
    for (int h = 0; h < 4; ++h)
        s += out3[((((size_t)(b * 4 + h) << 10) + n) << 6) + f];
    s *= 0.25f;
    float x = 1.0f / (1.0f + __expf(-s));
    float prod = x * hidden[(b << 6) + f];
    float logit = wred_sum(prod);
    if (f == 0) {
        dout[bn] = 1.0f / (1.0f + __expf(-logit));
        dout[17408 + bn] = logit;
    }
    if (n == 0) dout[16384 + (b << 6) + f] = hidden[(b << 6) + f];
}

// ---------------------------------------------------------------------------
extern "C" void kernel_launch(void* const* d_in, const int* in_sizes, int n_in,
                              void* d_out, int out_size, void* d_ws, size_t ws_size,
                              hipStream_t stream) {
    const int*   story  = (const int*)d_in[0];
    const int*   kb     = (const int*)d_in[1];
    const int*   cv     = (const int*)d_in[2];
    const float* hidden = (const float*)d_in[3];
    const float* dh     = (const float*)d_in[4];
    const float* adj    = (const float*)d_in[5];
    const float* emb    = (const float*)d_in[6];
    const float* W1     = (const float*)d_in[7];
    const float* a1     = (const float*)d_in[8];
    const float* W2     = (const float*)d_in[9];
    const float* a2     = (const float*)d_in[10];
    const float* W3     = (const float*)d_in[11];
    const float* a3     = (const float*)d_in[12];
    float* dout = (float*)d_out;

    char* ws = (char*)d_ws;
    u64*   mask = (u64*)(ws + 0);                 //  2 MB
    u16*   x0   = (u16*)(ws + 2097152);           //  4 MB
    u16*   xbf  = (u16*)(ws + 6291456);           //  8 MB
    float* Wh   = (float*)(ws + 14680064);        // 16 MB
    float* f1   = (float*)(ws + 31457280);        // 256 KB
    float* f2   = (float*)(ws + 31719424);        // 256 KB
    u16*   Bp   = (u16*)(ws + 31981568);          // 128 KB
    float* out3 = (float*)(ws + 32112640);        // 16 MB   (end ~48.9 MB)

    k_mask<<<4096, 256, 0, stream>>>(adj, kb, cv, mask);
    k_x0<<<16384, 128, 0, stream>>>(story, kb, cv, dh, emb, x0);

    // ---- layer 1 (K=128) ----
    k_prepW<<<16, 256, 0, stream>>>(W1, Bp, 128);
    k_gemm<4><<<256, 256, 0, stream>>>(x0, Bp, Wh);
    k_f12<<<16384, 256, 0, stream>>>(Wh, a1, f1, f2);
    k_pv<0><<<512, 256, 0, stream>>>(mask, f1, f2, Wh, xbf, nullptr);

    // ---- layer 2 (K=256) ----
    k_prepW<<<32, 256, 0, stream>>>(W2, Bp, 256);
    k_gemm<8><<<256, 256, 0, stream>>>(xbf, Bp, Wh);
    k_f12<<<16384, 256, 0, stream>>>(Wh, a2, f1, f2);
    k_pv<0><<<512, 256, 0, stream>>>(mask, f1, f2, Wh, xbf, nullptr);

    // ---- layer 3 (K=256, mean over heads) ----
    k_prepW<<<32, 256, 0, stream>>>(W3, Bp, 256);
    k_gemm<8><<<256, 256, 0, stream>>>(xbf, Bp, Wh);
    k_f12<<<16384, 256, 0, stream>>>(Wh, a3, f1, f2);
    k_pv<1><<<512, 256, 0, stream>>>(mask, f1, f2, Wh, nullptr, out3);

    k_final<<<16384, 64, 0, stream>>>(out3, hidden, dout);
}

// Round 2
// 409.221 us; speedup vs baseline: 5.8647x; 5.8647x over previous
//
#include <hip/hip_runtime.h>
#include <stdint.h>

typedef short bf16x8 __attribute__((ext_vector_type(8)));
typedef float f32x4 __attribute__((ext_vector_type(4)));
typedef unsigned int u32;
typedef unsigned int u32x4 __attribute__((ext_vector_type(4)));
typedef unsigned long long u64;
typedef unsigned short u16;

// B=16, N=1024, T=6, V=32000, D=128, F=64, H=4, LC=400

__device__ inline u16 f2b(float f) {
    unsigned u = __float_as_uint(f);
    u += 0x7fffu + ((u >> 16) & 1u);
    return (u16)(u >> 16);
}
__device__ inline float b2f(u16 h) { return __uint_as_float(((u32)h) << 16); }

__device__ inline float wred_sum(float v) {
    #pragma unroll
    for (int m = 32; m >= 1; m >>= 1) v += __shfl_xor(v, m, 64);
    return v;
}
__device__ inline float wred_max(float v) {
    #pragma unroll
    for (int m = 32; m >= 1; m >>= 1) v = fmaxf(v, __shfl_xor(v, m, 64));
    return v;
}

// ---------------------------------------------------------------------------
// K0: adjacency -> bitmask [B*N][16] u64, with diagonal fix (i>=start -> 1)
__global__ __launch_bounds__(256) void k_mask(const float* __restrict__ adj,
                                              const int* __restrict__ kb,
                                              const int* __restrict__ cv,
                                              u64* __restrict__ mask) {
    int tid = threadIdx.x;
    int w = tid >> 6, l = tid & 63;
    int row = blockIdx.x * 4 + w;            // b*1024 + i
    int b = row >> 10, i = row & 1023;
    int start = kb[b] + cv[b];
    const float* arow = adj + ((size_t)row << 10);
    u64* mrow = mask + ((size_t)row << 4);
    #pragma unroll
    for (int wd = 0; wd < 16; ++wd) {
        int j = (wd << 6) | l;
        bool p = arow[j] > 0.0f;
        if (j == i && i >= start) p = true;
        u64 bal = __ballot(p);
        if (l == 0) mrow[wd] = bal;
    }
}

// ---------------------------------------------------------------------------
// K1: x0 = sum_t emb[story] + (valid ? dh : 0), bf16 [B*N][128]
__global__ __launch_bounds__(128) void k_x0(const int* __restrict__ story,
                                            const int* __restrict__ kb,
                                            const int* __restrict__ cv,
                                            const float* __restrict__ dh,
                                            const float* __restrict__ emb,
                                            u16* __restrict__ x0) {
    int bn = blockIdx.x;
    int b = bn >> 10, n = bn & 1023;
    int d = threadIdx.x;
    const int* st = story + (size_t)bn * 6;
    float s = 0.0f;
    #pragma unroll
    for (int t = 0; t < 6; ++t) {
        int tok = st[t];
        s += emb[((size_t)tok << 7) + d];
    }
    int off = n - (kb[b] - 1);
    if (off >= 0 && off < cv[b]) s += dh[((size_t)b * 400 + off) * 128 + d];
    x0[((size_t)bn << 7) + d] = f2b(s);
}

// ---------------------------------------------------------------------------
// K2: pack W [H][K][64] fp32 -> MFMA B-fragment layout bf16
__global__ __launch_bounds__(256) void k_prepW(const float* __restrict__ W,
                                               u16* __restrict__ Bpack, int K) {
    int id = blockIdx.x * 256 + threadIdx.x;
    if (id >= K * 32) return;
    int lane = id & 63;
    int ctk = id >> 6;
    int ct = ctk & 15, kt = ctk >> 4;
    int col = (ct << 4) | (lane & 15);
    int h = col >> 6, f = col & 63;
    int kbase = (kt << 5) + ((lane >> 4) << 3);
    u16* o = Bpack + (size_t)id * 8;
    #pragma unroll
    for (int j = 0; j < 8; ++j) {
        o[j] = f2b(W[((size_t)h * K + kbase + j) * 64 + f]);
    }
}

// ---------------------------------------------------------------------------
// K3: Whb[16384][256] (bf16) = A[16384][K] (bf16) @ Wcat[K][256]
template <int KT>
__global__ __launch_bounds__(256) void k_gemm(const u16* __restrict__ A,
                                              const u16* __restrict__ Bp,
                                              u16* __restrict__ Whb) {
    constexpr int K = KT * 32;
    int tid = threadIdx.x;
    int w = tid >> 6, l = tid & 63;
    int rt = blockIdx.x * 4 + w;
    int m0 = rt << 4;
    const bf16x8* Av = (const bf16x8*)A;
    const bf16x8* Bv = (const bf16x8*)Bp;
    int arow = m0 + (l & 15);
    bf16x8 af[KT];
    #pragma unroll
    for (int kt = 0; kt < KT; ++kt)
        af[kt] = Av[(((size_t)arow * K) + (kt << 5) + ((l >> 4) << 3)) >> 3];
    int ro = (l >> 4) << 2;
    int co = l & 15;
    for (int ct = 0; ct < 16; ++ct) {
        f32x4 acc = {0.f, 0.f, 0.f, 0.f};
        #pragma unroll
        for (int kt = 0; kt < KT; ++kt)
            acc = __builtin_amdgcn_mfma_f32_16x16x32_bf16(af[kt], Bv[(kt * 16 + ct) * 64 + l], acc, 0, 0, 0);
        int col = (ct << 4) + co;
        #pragma unroll
        for (int j = 0; j < 4; ++j)
            Whb[(size_t)(m0 + ro + j) * 256 + col] = f2b(acc[j]);
    }
}

// ---------------------------------------------------------------------------
// K4: f1[b,h,n] = Whb[b,n,h*64+f] . a[h][f], f2 with a[h][64+f]
__global__ __launch_bounds__(256) void k_f12(const u16* __restrict__ Whb,
                                             const float* __restrict__ a,
                                             float* __restrict__ f1,
                                             float* __restrict__ f2) {
    int bn = blockIdx.x;
    int t = threadIdx.x;
    int h = t >> 6, f = t & 63;
    float v = b2f(Whb[((size_t)bn << 8) + t]);
    float p1 = v * a[h * 128 + f];
    float p2 = v * a[h * 128 + 64 + f];
    p1 = wred_sum(p1);
    p2 = wred_sum(p2);
    if (f == 0) {
        int b = bn >> 10, n = bn & 1023;
        int o = ((b * 4 + h) << 10) + n;
        f1[o] = p1;
        f2[o] = p2;
    }
}

// ---------------------------------------------------------------------------
// K4b: per (b,h,row): emax = lrelu(f1 + max_{j in nbr} f2_j), deg0 flag.
// One wave per row.
__global__ __launch_bounds__(256) void k_emax(const u64* __restrict__ mask,
                                              const float* __restrict__ f1g,
                                              const float* __restrict__ f2g,
                                              float* __restrict__ emaxg,
                                              float* __restrict__ d0g) {
    int tid = threadIdx.x;
    int w = tid >> 6, l = tid & 63;
    int gw = blockIdx.x * 4 + w;             // bh*1024 + i
    int bh = gw >> 10, i = gw & 1023;
    int b = bh >> 2;
    const u64* mrow = mask + (((size_t)(b << 10) + i) << 4);
    float mloc = -3.0e38f;
    float dloc = 0.0f;
    #pragma unroll
    for (int wd = 0; wd < 16; ++wd) {
        u64 word = mrow[wd];
        u32 bit = (u32)(word >> l) & 1u;
        float f2v = f2g[(bh << 10) + (wd << 6) + l];
        dloc += (float)bit;
        if (bit) mloc = fmaxf(mloc, f2v);
    }
    mloc = wred_max(mloc);
    dloc = wred_sum(dloc);
    if (l == 0) {
        float m = dloc > 0.0f ? mloc : 0.0f;
        float e = f1g[gw] + m;
        e = fmaxf(e, 0.2f * e);
        emaxg[gw] = e;
        d0g[gw] = dloc > 0.0f ? 0.0f : 1.0f;
    }
}

// ---------------------------------------------------------------------------
// K4c: pack Whb bf16 -> per (b,h,jt,ft) MFMA B-fragments
__global__ __launch_bounds__(256) void k_packWh(const u16* __restrict__ Whb,
                                                u16* __restrict__ WhB) {
    int id = blockIdx.x * 256 + threadIdx.x;   // frag*64 + lane; 8192*64 total
    int l = id & 63;
    int frag = id >> 6;
    int ft = frag & 3, jt = (frag >> 2) & 31, bh = frag >> 7;
    int b = bh >> 2, h = bh & 3;
    int row0 = (b << 10) + (jt << 5) + ((l >> 4) << 3);
    int col = (h << 6) + (ft << 4) + (l & 15);
    u16 o[8];
    #pragma unroll
    for (int jj = 0; jj < 8; ++jj) o[jj] = Whb[((size_t)(row0 + jj) << 8) + col];
    *(bf16x8*)(WhB + (size_t)id * 8) = *(const bf16x8*)o;
}

// ---------------------------------------------------------------------------
// K5: dense masked softmax + PV via MFMA. One wave = one 16-row i-tile.
// P generated in registers in A-fragment layout; Wh B-fragments pre-packed.
template <int MODE>
__global__ __launch_bounds__(256) void k_pv(const u32* __restrict__ mask32,
                                            const float* __restrict__ f1g,
                                            const float* __restrict__ f2g,
                                            const float* __restrict__ emaxg,
                                            const float* __restrict__ d0g,
                                            const bf16x8* __restrict__ Bv,
                                            u16* __restrict__ xout,
                                            float* __restrict__ out3) {
    __shared__ __align__(16) float f2s[1024];
    int tid = threadIdx.x;
    int w = tid >> 6, l = tid & 63;
    int bh = blockIdx.x >> 4;
    int b = bh >> 2, h = bh & 3;
    int itile = ((blockIdx.x & 15) << 2) + w;
    int i0 = itile << 4;
    for (int idx = tid; idx < 1024; idx += 256) f2s[idx] = f2g[(bh << 10) + idx];
    __syncthreads();
    int row = l & 15;
    int g = l >> 4;
    int i = i0 + row;
    float f1i = f1g[(bh << 10) + i];
    float emaxi = emaxg[(bh << 10) + i];
    float d0f = d0g[(bh << 10) + i];
    const u32* mrow = mask32 + (((size_t)(b << 10) + i) << 5);
    f32x4 acc[4];
    #pragma unroll
    for (int ft = 0; ft < 4; ++ft) acc[ft] = f32x4{0.f, 0.f, 0.f, 0.f};
    float ss = 0.0f;
    const f32x4* f2v4 = (const f32x4*)f2s;
    int fragbase = (bh << 7);                  // bh*128 + jt*4 + ft
    for (int jt = 0; jt < 32; ++jt) {
        u32 mword = mrow[jt];
        f32x4 fa = f2v4[(jt << 3) + (g << 1)];
        f32x4 fb = f2v4[(jt << 3) + (g << 1) + 1];
        float p[8];
        #pragma unroll
        for (int jj = 0; jj < 8; ++jj) {
            float f2j = (jj < 4) ? fa[jj & 3] : fb[jj & 3];
            float e = f1i + f2j;
            e = fmaxf(e, 0.2f * e);
            float ex = __expf(e - emaxi);
            u32 bit = (mword >> ((g << 3) + jj)) & 1u;
            float pv = bit ? ex : d0f;
            p[jj] = pv;
            ss += pv;
        }
        u32x4 pk;
        #pragma unroll
        for (int q = 0; q < 4; ++q) {
            u32 lo = __float_as_uint(p[2 * q]);
            u32 hi = __float_as_uint(p[2 * q + 1]);
            pk[q] = ((lo + 0x8000u) >> 16) | ((hi + 0x8000u) & 0xffff0000u);
        }
        bf16x8 af = __builtin_bit_cast(bf16x8, pk);
        #pragma unroll
        for (int ft = 0; ft < 4; ++ft)
            acc[ft] = __builtin_amdgcn_mfma_f32_16x16x32_bf16(
                af, Bv[(size_t)(fragbase + (jt << 2) + ft) * 64 + l], acc[ft], 0, 0, 0);
    }
    ss += __shfl_xor(ss, 16, 64);
    ss += __shfl_xor(ss, 32, 64);
    #pragma unroll
    for (int reg = 0; reg < 4; ++reg) {
        int orow = (g << 2) + reg;
        float s = __shfl(ss, orow, 64);
        float rinv = 1.0f / s;
        int grow = i0 + orow;
        #pragma unroll
        for (int ft = 0; ft < 4; ++ft) {
            float v = acc[ft][reg] * rinv;
            if (MODE == 0) {
                float e = v > 0.0f ? v : (__expf(v) - 1.0f);   // elu
                xout[((size_t)((b << 10) + grow) << 8) + (h << 6) + (ft << 4) + row] = f2b(e);
            } else {
                out3[((size_t)((bh << 10) + grow) << 6) + (ft << 4) + row] = v;
            }
        }
    }
}

// ---------------------------------------------------------------------------
// K6: final head-mean -> sigmoid -> dot(hidden) -> outputs
__global__ __launch_bounds__(64) void k_final(const float* __restrict__ out3,
                                              const float* __restrict__ hidden,
                                              float* __restrict__ dout) {
    int bn = blockIdx.x;
    int b = bn >> 10, n = bn & 1023;
    int f = threadIdx.x;
    float s = 0.0f;
    #pragma unroll
    for (int h = 0; h < 4; ++h)
        s += out3[((((size_t)(b * 4 + h) << 10) + n) << 6) + f];
    s *= 0.25f;
    float x = 1.0f / (1.0f + __expf(-s));
    float prod = x * hidden[(b << 6) + f];
    float logit = wred_sum(prod);
    if (f == 0) {
        dout[bn] = 1.0f / (1.0f + __expf(-logit));
        dout[17408 + bn] = logit;
    }
    if (n == 0) dout[16384 + (b << 6) + f] = hidden[(b << 6) + f];
}

// ---------------------------------------------------------------------------
extern "C" void kernel_launch(void* const* d_in, const int* in_sizes, int n_in,
                              void* d_out, int out_size, void* d_ws, size_t ws_size,
                              hipStream_t stream) {
    const int*   story  = (const int*)d_in[0];
    const int*   kb     = (const int*)d_in[1];
    const int*   cv     = (const int*)d_in[2];
    const float* hidden = (const float*)d_in[3];
    const float* dh     = (const float*)d_in[4];
    const float* adj    = (const float*)d_in[5];
    const float* emb    = (const float*)d_in[6];
    const float* W1     = (const float*)d_in[7];
    const float* a1     = (const float*)d_in[8];
    const float* W2     = (const float*)d_in[9];
    const float* a2     = (const float*)d_in[10];
    const float* W3     = (const float*)d_in[11];
    const float* a3     = (const float*)d_in[12];
    float* dout = (float*)d_out;

    char* ws = (char*)d_ws;
    u64*   mask = (u64*)(ws + 0);                 //  2 MB
    u32*   mask32 = (u32*)(ws + 0);               //  alias
    u16*   x0   = (u16*)(ws + 2097152);           //  4 MB
    u16*   xbf  = (u16*)(ws + 6291456);           //  8 MB  (dead after L3 gemm)
    u16*   Whb  = (u16*)(ws + 14680064);          //  8 MB  (dead after packWh/f12)
    u16*   WhB  = (u16*)(ws + 23068672);          //  8 MB  packed B-fragments
    float* f1   = (float*)(ws + 31457280);        //  256 KB
    float* f2   = (float*)(ws + 31719424);        //  256 KB
    float* emx  = (float*)(ws + 31981568);        //  256 KB
    float* d0g  = (float*)(ws + 32243712);        //  256 KB
    u16*   Bp   = (u16*)(ws + 32505856);          //  128 KB
    float* out3 = (float*)(ws + 6291456);         //  16.8 MB, overlaps xbf+Whb (both dead)

    k_mask<<<4096, 256, 0, stream>>>(adj, kb, cv, mask);
    k_x0<<<16384, 128, 0, stream>>>(story, kb, cv, dh, emb, x0);

    // ---- layer 1 (K=128) ----
    k_prepW<<<16, 256, 0, stream>>>(W1, Bp, 128);
    k_gemm<4><<<256, 256, 0, stream>>>(x0, Bp, Whb);
    k_f12<<<16384, 256, 0, stream>>>(Whb, a1, f1, f2);
    k_emax<<<16384, 256, 0, stream>>>(mask, f1, f2, emx, d0g);
    k_packWh<<<2048, 256, 0, stream>>>(Whb, WhB);
    k_pv<0><<<1024, 256, 0, stream>>>(mask32, f1, f2, emx, d0g, (const bf16x8*)WhB, xbf, nullptr);

    // ---- layer 2 (K=256) ----
    k_prepW<<<32, 256, 0, stream>>>(W2, Bp, 256);
    k_gemm<8><<<256, 256, 0, stream>>>(xbf, Bp, Whb);
    k_f12<<<16384, 256, 0, stream>>>(Whb, a2, f1, f2);
    k_emax<<<16384, 256, 0, stream>>>(mask, f1, f2, emx, d0g);
    k_packWh<<<2048, 256, 0, stream>>>(Whb, WhB);
    k_pv<0><<<1024, 256, 0, stream>>>(mask32, f1, f2, emx, d0g, (const bf16x8*)WhB, xbf, nullptr);

    // ---- layer 3 (K=256, mean over heads) ----
    k_prepW<<<32, 256, 0, stream>>>(W3, Bp, 256);
    k_gemm<8><<<256, 256, 0, stream>>>(xbf, Bp, Whb);
    k_f12<<<16384, 256, 0, stream>>>(Whb, a3, f1, f2);
    k_emax<<<16384, 256, 0, stream>>>(mask, f1, f2, emx, d0g);
    k_packWh<<<2048, 256, 0, stream>>>(Whb, WhB);
    k_pv<1><<<1024, 256, 0, stream>>>(mask32, f1, f2, emx, d0g, (const bf16x8*)WhB, nullptr, out3);

    k_final<<<16384, 64, 0, stream>>>(out3, hidden, dout);
}

// Round 3
// 228.378 us; speedup vs baseline: 10.5088x; 1.7919x over previous
//
#include <hip/hip_runtime.h>
#include <stdint.h>

typedef short bf16x8 __attribute__((ext_vector_type(8)));
typedef float f32x4 __attribute__((ext_vector_type(4)));
typedef unsigned short u16;
typedef unsigned short u16x4 __attribute__((ext_vector_type(4)));
typedef unsigned int u32;
typedef unsigned int u32x4 __attribute__((ext_vector_type(4)));
typedef unsigned long long u64;

// B=16, N=1024, T=6, V=32000, D=128, F=64, H=4, LC=400

__device__ inline u16 f2b(float f) {
    unsigned u = __float_as_uint(f);
    u += 0x7fffu + ((u >> 16) & 1u);
    return (u16)(u >> 16);
}

__device__ inline float wred_sum(float v) {
    #pragma unroll
    for (int m = 32; m >= 1; m >>= 1) v += __shfl_xor(v, m, 64);
    return v;
}

// ---------------------------------------------------------------------------
// K0: adjacency -> bitmask [B*N][16] u64, with diagonal fix (i>=start -> 1)
__global__ __launch_bounds__(256) void k_mask(const float* __restrict__ adj,
                                              const int* __restrict__ kb,
                                              const int* __restrict__ cv,
                                              u64* __restrict__ mask) {
    int tid = threadIdx.x;
    int w = tid >> 6, l = tid & 63;
    int row = blockIdx.x * 4 + w;            // b*1024 + i
    int b = row >> 10, i = row & 1023;
    int start = kb[b] + cv[b];
    const float* arow = adj + ((size_t)row << 10);
    u64* mrow = mask + ((size_t)row << 4);
    #pragma unroll
    for (int wd = 0; wd < 16; ++wd) {
        int j = (wd << 6) | l;
        bool p = arow[j] > 0.0f;
        if (j == i && i >= start) p = true;
        u64 bal = __ballot(p);
        if (l == 0) mrow[wd] = bal;
    }
}

// ---------------------------------------------------------------------------
// K1: x0 = sum_t emb[story] + (valid ? dh : 0), bf16 [B*N][128]
__global__ __launch_bounds__(128) void k_x0(const int* __restrict__ story,
                                            const int* __restrict__ kb,
                                            const int* __restrict__ cv,
                                            const float* __restrict__ dh,
                                            const float* __restrict__ emb,
                                            u16* __restrict__ x0) {
    int bn = blockIdx.x;
    int b = bn >> 10, n = bn & 1023;
    int d = threadIdx.x;
    const int* st = story + (size_t)bn * 6;
    float s = 0.0f;
    #pragma unroll
    for (int t = 0; t < 6; ++t) {
        int tok = st[t];
        s += emb[((size_t)tok << 7) + d];
    }
    int off = n - (kb[b] - 1);
    if (off >= 0 && off < cv[b]) s += dh[((size_t)b * 400 + off) * 128 + d];
    x0[((size_t)bn << 7) + d] = f2b(s);
}

// ---------------------------------------------------------------------------
// K2: pack W [H][K][64] fp32 -> MFMA B-fragments, 17 column-tiles per kt.
//     ct 0..15: Wcat columns. ct 16: cols 0..7 = wa vectors (W[h]@a[h,half]),
//     giving f1/f2 as GEMM outputs; cols 8..15 zero.
__global__ __launch_bounds__(256) void k_prepW(const float* __restrict__ W,
                                               const float* __restrict__ a,
                                               u16* __restrict__ Bpack, int K) {
    int id = blockIdx.x * 256 + threadIdx.x;
    int total = (K >> 5) * 17 * 64;
    if (id >= total) return;
    int lane = id & 63;
    int fr = id >> 6;
    int kt = fr / 17, ct = fr - kt * 17;
    int kbase = (kt << 5) + ((lane >> 4) << 3);
    u16 o[8];
    if (ct < 16) {
        int col = (ct << 4) | (lane & 15);
        int h = col >> 6, f = col & 63;
        #pragma unroll
        for (int j = 0; j < 8; ++j)
            o[j] = f2b(W[((size_t)h * K + kbase + j) * 64 + f]);
    } else {
        int c = lane & 15;
        if (c < 8) {
            int h = c >> 1, which = c & 1;
            const float* av = a + h * 128 + which * 64;
            #pragma unroll
            for (int j = 0; j < 8; ++j) {
                const float* wr = W + ((size_t)h * K + kbase + j) * 64;
                float s = 0.0f;
                for (int f = 0; f < 64; ++f) s += wr[f] * av[f];
                o[j] = f2b(s);
            }
        } else {
            #pragma unroll
            for (int j = 0; j < 8; ++j) o[j] = 0;
        }
    }
    *(bf16x8*)(Bpack + (size_t)id * 8) = *(const bf16x8*)o;
}

// ---------------------------------------------------------------------------
// K3: fused GEMM: Wh = A @ Wcat (bf16, MFMA) -> writes
//     (a) WhB MFMA B-fragments (via per-wave LDS transpose),
//     (b) f1/f2 (from the 17th column-tile).
//     Wave = 16 rows x 128 cols (colhalf), grid 512 blocks x 4 waves.
template <int KT>
__global__ __launch_bounds__(256) void k_gemm(const u16* __restrict__ A,
                                              const u16* __restrict__ Bp,
                                              u16* __restrict__ WhB,
                                              float* __restrict__ f1,
                                              float* __restrict__ f2) {
    constexpr int K = KT * 32;
    __shared__ __align__(16) u16 tile[4][2048];   // [wave][col2*16 + row]
    int tid = threadIdx.x;
    int w = tid >> 6, l = tid & 63;
    int gw = blockIdx.x * 4 + w;
    int rt = gw >> 1, colhalf = gw & 1;
    int m0 = rt << 4;
    int b = m0 >> 10, n0 = m0 & 1023;
    int jt = n0 >> 5, halfsel = (n0 >> 4) & 1;
    const bf16x8* Av = (const bf16x8*)A;
    const bf16x8* Bv = (const bf16x8*)Bp;
    int arow = m0 + (l & 15);
    bf16x8 af[KT];
    #pragma unroll
    for (int kt = 0; kt < KT; ++kt)
        af[kt] = Av[((size_t)arow * K + (kt << 5) + ((l >> 4) << 3)) >> 3];
    f32x4 acc[8];
    #pragma unroll
    for (int c = 0; c < 8; ++c) acc[c] = f32x4{0.f, 0.f, 0.f, 0.f};
    f32x4 acc16 = {0.f, 0.f, 0.f, 0.f};
    #pragma unroll
    for (int kt = 0; kt < KT; ++kt) {
        #pragma unroll
        for (int c = 0; c < 8; ++c) {
            int ct = (colhalf << 3) + c;
            acc[c] = __builtin_amdgcn_mfma_f32_16x16x32_bf16(
                af[kt], Bv[(kt * 17 + ct) * 64 + l], acc[c], 0, 0, 0);
        }
        if (colhalf == 0)
            acc16 = __builtin_amdgcn_mfma_f32_16x16x32_bf16(
                af[kt], Bv[(kt * 17 + 16) * 64 + l], acc16, 0, 0, 0);
    }
    int co = l & 15, ro = (l >> 4) << 2;
    // f1/f2 outputs (cols 256 + h*2 + which)
    if (colhalf == 0 && co < 8) {
        int h = co >> 1;
        float* fp = (co & 1) ? f2 : f1;
        int base = (((b << 2) + h) << 10) + n0 + ro;
        #pragma unroll
        for (int r = 0; r < 4; ++r) fp[base + r] = acc16[r];
    }
    // LDS transpose: acc -> bf16 tile [col2][row]
    u16* tw = tile[w];
    #pragma unroll
    for (int c = 0; c < 8; ++c) {
        int col2 = (c << 4) + co;
        u16x4 pk;
        #pragma unroll
        for (int r = 0; r < 4; ++r) pk[r] = f2b(acc[c][r]);
        *(u16x4*)(tw + (col2 << 4) + ro) = pk;
    }
    __syncthreads();
    // emit MFMA B-fragments of Wh
    int lp = (halfsel << 5) + (l & 31);
    #pragma unroll
    for (int c4 = 0; c4 < 4; ++c4) {
        int combo = (c4 << 1) + (l >> 5);
        int hh = combo >> 2, ft = combo & 3;
        int col2 = (hh << 6) + (ft << 4) + (l & 15);
        int r0 = ((l >> 4) & 1) << 3;
        bf16x8 v = *(const bf16x8*)(tw + (col2 << 4) + r0);
        int h = (colhalf << 1) + hh;
        int bh = (b << 2) + h;
        size_t fidx = (size_t)((bh << 7) + (jt << 2) + ft);
        *(bf16x8*)(WhB + (fidx * 64 + lp) * 8) = v;
    }
}

// ---------------------------------------------------------------------------
// K5: dense masked softmax + PV via MFMA, with fused neighbor-max pre-pass.
// One wave = one 16-row i-tile. Mask words cached in VGPRs, f2 in LDS.
template <int MODE>
__global__ __launch_bounds__(256) void k_pv(const u32* __restrict__ mask32,
                                            const float* __restrict__ f1g,
                                            const float* __restrict__ f2g,
                                            const bf16x8* __restrict__ Bv,
                                            u16* __restrict__ xout,
                                            float* __restrict__ out3) {
    __shared__ __align__(16) float f2s[1024];
    int tid = threadIdx.x;
    int w = tid >> 6, l = tid & 63;
    int bh = blockIdx.x >> 4;
    int b = bh >> 2, h = bh & 3;
    int itile = ((blockIdx.x & 15) << 2) + w;
    int i0 = itile << 4;
    for (int idx = tid; idx < 1024; idx += 256) f2s[idx] = f2g[(bh << 10) + idx];
    __syncthreads();
    int row = l & 15;
    int g = l >> 4;
    int i = i0 + row;
    float f1i = f1g[(bh << 10) + i];
    const u32* mrow = mask32 + (((size_t)(b << 10) + i) << 5);
    u32 mw[32];
    #pragma unroll
    for (int jt = 0; jt < 32; ++jt) mw[jt] = mrow[jt];
    const f32x4* f2v4 = (const f32x4*)f2s;
    // pass 1: neighbor max of f2 (lane covers its 8 j's per word)
    float mloc = -3.0e38f;
    #pragma unroll
    for (int jt = 0; jt < 32; ++jt) {
        u32 bits = mw[jt] >> (g << 3);
        f32x4 fa = f2v4[(jt << 3) + (g << 1)];
        f32x4 fb = f2v4[(jt << 3) + (g << 1) + 1];
        #pragma unroll
        for (int jj = 0; jj < 4; ++jj)
            if ((bits >> jj) & 1) mloc = fmaxf(mloc, fa[jj]);
        #pragma unroll
        for (int jj = 0; jj < 4; ++jj)
            if ((bits >> (4 + jj)) & 1) mloc = fmaxf(mloc, fb[jj]);
    }
    mloc = fmaxf(mloc, __shfl_xor(mloc, 16, 64));
    mloc = fmaxf(mloc, __shfl_xor(mloc, 32, 64));
    float d0f = (mloc < -1.0e38f) ? 1.0f : 0.0f;   // deg==0 -> uniform softmax
    float mm = (d0f > 0.0f) ? 0.0f : mloc;
    float e0 = f1i + mm;
    float emaxi = fmaxf(e0, 0.2f * e0);            // lrelu (monotonic)
    // pass 2: p = exp(lrelu(f1+f2) - emax) -> bf16 A-fragments -> MFMA PV
    f32x4 acc[4];
    #pragma unroll
    for (int ft = 0; ft < 4; ++ft) acc[ft] = f32x4{0.f, 0.f, 0.f, 0.f};
    float ss = 0.0f;
    int fragbase = (bh << 7);
    for (int jt = 0; jt < 32; ++jt) {
        u32 mword = mw[jt];
        f32x4 fa = f2v4[(jt << 3) + (g << 1)];
        f32x4 fb = f2v4[(jt << 3) + (g << 1) + 1];
        float p[8];
        #pragma unroll
        for (int jj = 0; jj < 8; ++jj) {
            float f2j = (jj < 4) ? fa[jj & 3] : fb[jj & 3];
            float e = f1i + f2j;
            e = fmaxf(e, 0.2f * e);
            float ex = __expf(e - emaxi);
            u32 bit = (mword >> ((g << 3) + jj)) & 1u;
            float pv = bit ? ex : d0f;
            p[jj] = pv;
            ss += pv;
        }
        u32x4 pk;
        #pragma unroll
        for (int q = 0; q < 4; ++q) {
            u32 lo = __float_as_uint(p[2 * q]);
            u32 hi = __float_as_uint(p[2 * q + 1]);
            pk[q] = ((lo + 0x8000u) >> 16) | ((hi + 0x8000u) & 0xffff0000u);
        }
        bf16x8 af = __builtin_bit_cast(bf16x8, pk);
        #pragma unroll
        for (int ft = 0; ft < 4; ++ft)
            acc[ft] = __builtin_amdgcn_mfma_f32_16x16x32_bf16(
                af, Bv[(size_t)(fragbase + (jt << 2) + ft) * 64 + l], acc[ft], 0, 0, 0);
    }
    ss += __shfl_xor(ss, 16, 64);
    ss += __shfl_xor(ss, 32, 64);
    #pragma unroll
    for (int reg = 0; reg < 4; ++reg) {
        int orow = (g << 2) + reg;
        float s = __shfl(ss, orow, 64);
        float rinv = 1.0f / s;
        int grow = i0 + orow;
        #pragma unroll
        for (int ft = 0; ft < 4; ++ft) {
            float v = acc[ft][reg] * rinv;
            if (MODE == 0) {
                float e = v > 0.0f ? v : (__expf(v) - 1.0f);   // elu
                xout[((size_t)((b << 10) + grow) << 8) + (h << 6) + (ft << 4) + row] = f2b(e);
            } else {
                out3[((size_t)((bh << 10) + grow) << 6) + (ft << 4) + row] = v;
            }
        }
    }
}

// ---------------------------------------------------------------------------
// K6: final head-mean -> sigmoid -> dot(hidden) -> outputs
__global__ __launch_bounds__(64) void k_final(const float* __restrict__ out3,
                                              const float* __restrict__ hidden,
                                              float* __restrict__ dout) {
    int bn = blockIdx.x;
    int b = bn >> 10, n = bn & 1023;
    int f = threadIdx.x;
    float s = 0.0f;
    #pragma unroll
    for (int h = 0; h < 4; ++h)
        s += out3[((((size_t)(b * 4 + h) << 10) + n) << 6) + f];
    s *= 0.25f;
    float x = 1.0f / (1.0f + __expf(-s));
    float prod = x * hidden[(b << 6) + f];
    float logit = wred_sum(prod);
    if (f == 0) {
        dout[bn] = 1.0f / (1.0f + __expf(-logit));
        dout[17408 + bn] = logit;
    }
    if (n == 0) dout[16384 + (b << 6) + f] = hidden[(b << 6) + f];
}

// ---------------------------------------------------------------------------
extern "C" void kernel_launch(void* const* d_in, const int* in_sizes, int n_in,
                              void* d_out, int out_size, void* d_ws, size_t ws_size,
                              hipStream_t stream) {
    const int*   story  = (const int*)d_in[0];
    const int*   kb     = (const int*)d_in[1];
    const int*   cv     = (const int*)d_in[2];
    const float* hidden = (const float*)d_in[3];
    const float* dh     = (const float*)d_in[4];
    const float* adj    = (const float*)d_in[5];
    const float* emb    = (const float*)d_in[6];
    const float* W1     = (const float*)d_in[7];
    const float* a1     = (const float*)d_in[8];
    const float* W2     = (const float*)d_in[9];
    const float* a2     = (const float*)d_in[10];
    const float* W3     = (const float*)d_in[11];
    const float* a3     = (const float*)d_in[12];
    float* dout = (float*)d_out;

    char* ws = (char*)d_ws;
    u64*   mask   = (u64*)(ws + 0);               //  2 MB
    u32*   mask32 = (u32*)(ws + 0);               //  alias
    u16*   x0   = (u16*)(ws + 2097152);           //  4 MB
    u16*   xbf  = (u16*)(ws + 6291456);           //  8 MB
    u16*   WhB  = (u16*)(ws + 14680064);          //  8 MB packed B-fragments
    float* f1   = (float*)(ws + 23068672);        //  256 KB
    float* f2   = (float*)(ws + 23330816);        //  256 KB
    u16*   Bp   = (u16*)(ws + 23592960);          //  272 KB
    float* out3 = (float*)(ws + 23871488);        //  16 MB (end ~40.6 MB)

    k_mask<<<4096, 256, 0, stream>>>(adj, kb, cv, mask);
    k_x0<<<16384, 128, 0, stream>>>(story, kb, cv, dh, emb, x0);

    // ---- layer 1 (K=128) ----
    k_prepW<<<17, 256, 0, stream>>>(W1, a1, Bp, 128);
    k_gemm<4><<<512, 256, 0, stream>>>(x0, Bp, WhB, f1, f2);
    k_pv<0><<<1024, 256, 0, stream>>>(mask32, f1, f2, (const bf16x8*)WhB, xbf, nullptr);

    // ---- layer 2 (K=256) ----
    k_prepW<<<34, 256, 0, stream>>>(W2, a2, Bp, 256);
    k_gemm<8><<<512, 256, 0, stream>>>(xbf, Bp, WhB, f1, f2);
    k_pv<0><<<1024, 256, 0, stream>>>(mask32, f1, f2, (const bf16x8*)WhB, xbf, nullptr);

    // ---- layer 3 (K=256, mean over heads) ----
    k_prepW<<<34, 256, 0, stream>>>(W3, a3, Bp, 256);
    k_gemm<8><<<512, 256, 0, stream>>>(xbf, Bp, WhB, f1, f2);
    k_pv<1><<<1024, 256, 0, stream>>>(mask32, f1, f2, (const bf16x8*)WhB, nullptr, out3);

    k_final<<<16384, 64, 0, stream>>>(out3, hidden, dout);
}

// Round 4
// 182.774 us; speedup vs baseline: 13.1308x; 1.2495x over previous
//
#include <hip/hip_runtime.h>
#include <stdint.h>

typedef short bf16x8 __attribute__((ext_vector_type(8)));
typedef float f32x4 __attribute__((ext_vector_type(4)));
typedef unsigned short u16;
typedef unsigned short u16x4 __attribute__((ext_vector_type(4)));
typedef unsigned int u32;
typedef unsigned int u32x4 __attribute__((ext_vector_type(4)));
typedef unsigned long long u64;

// B=16, N=1024, T=6, V=32000, D=128, F=64, H=4, LC=400

__device__ inline u16 f2b(float f) {
    unsigned u = __float_as_uint(f);
    u += 0x7fffu + ((u >> 16) & 1u);
    return (u16)(u >> 16);
}

__device__ inline float wred_sum(float v) {
    #pragma unroll
    for (int m = 32; m >= 1; m >>= 1) v += __shfl_xor(v, m, 64);
    return v;
}

// ---------------------------------------------------------------------------
// K0: adjacency -> bitmask [B*N][16] u64, with diagonal fix (i>=start -> 1)
__global__ __launch_bounds__(256) void k_mask(const float* __restrict__ adj,
                                              const int* __restrict__ kb,
                                              const int* __restrict__ cv,
                                              u64* __restrict__ mask) {
    int tid = threadIdx.x;
    int w = tid >> 6, l = tid & 63;
    int row = blockIdx.x * 4 + w;            // b*1024 + i
    int b = row >> 10, i = row & 1023;
    int start = kb[b] + cv[b];
    const float* arow = adj + ((size_t)row << 10);
    u64* mrow = mask + ((size_t)row << 4);
    #pragma unroll
    for (int wd = 0; wd < 16; ++wd) {
        int j = (wd << 6) | l;
        bool p = arow[j] > 0.0f;
        if (j == i && i >= start) p = true;
        u64 bal = __ballot(p);
        if (l == 0) mrow[wd] = bal;
    }
}

// ---------------------------------------------------------------------------
// K1: x0 = sum_t emb[story] + (valid ? dh : 0), bf16 [B*N][128]
__global__ __launch_bounds__(128) void k_x0(const int* __restrict__ story,
                                            const int* __restrict__ kb,
                                            const int* __restrict__ cv,
                                            const float* __restrict__ dh,
                                            const float* __restrict__ emb,
                                            u16* __restrict__ x0) {
    int bn = blockIdx.x;
    int b = bn >> 10, n = bn & 1023;
    int d = threadIdx.x;
    const int* st = story + (size_t)bn * 6;
    float s = 0.0f;
    #pragma unroll
    for (int t = 0; t < 6; ++t) {
        int tok = st[t];
        s += emb[((size_t)tok << 7) + d];
    }
    int off = n - (kb[b] - 1);
    if (off >= 0 && off < cv[b]) s += dh[((size_t)b * 400 + off) * 128 + d];
    x0[((size_t)bn << 7) + d] = f2b(s);
}

// ---------------------------------------------------------------------------
// K2a: wa[c][k] = W[h][k][:] . a[h][half], c = h*2+half. One thread per dot.
__global__ __launch_bounds__(256) void k_wa(const float* __restrict__ W,
                                            const float* __restrict__ a,
                                            float* __restrict__ wa,
                                            int Kmask, int kshift) {
    int id = blockIdx.x * 256 + threadIdx.x;
    int c = id >> kshift, k = id & Kmask;
    int h = c >> 1, wh = c & 1;
    const float4* wr = (const float4*)(W + ((size_t)(h << kshift) + k) * 64);
    const float4* av = (const float4*)(a + h * 128 + wh * 64);
    float s = 0.0f;
    #pragma unroll
    for (int q = 0; q < 16; ++q) {
        float4 x = wr[q], y = av[q];
        s += x.x * y.x + x.y * y.y + x.z * y.z + x.w * y.w;
    }
    wa[id] = s;
}

// ---------------------------------------------------------------------------
// K2b: pack W [H][K][64] fp32 -> MFMA B-fragments, 17 column-tiles per kt.
//     ct 0..15: Wcat columns. ct 16: cols 0..7 = wa vectors; cols 8..15 zero.
//     One thread per output u16.
__global__ __launch_bounds__(256) void k_prepW(const float* __restrict__ W,
                                               const float* __restrict__ wa,
                                               u16* __restrict__ Bpack, int K) {
    int id = blockIdx.x * 256 + threadIdx.x;
    int total = (K >> 5) * 17 * 512;
    if (id >= total) return;
    int j = id & 7, lane = (id >> 3) & 63, fr = id >> 9;
    int kt = fr / 17, ct = fr - kt * 17;
    int kk = (kt << 5) + ((lane >> 4) << 3) + j;
    u16 o;
    if (ct < 16) {
        int col = (ct << 4) | (lane & 15);
        o = f2b(W[((size_t)(col >> 6) * K + kk) * 64 + (col & 63)]);
    } else {
        int c = lane & 15;
        o = (c < 8) ? f2b(wa[c * K + kk]) : (u16)0;
    }
    Bpack[id] = o;
}

// ---------------------------------------------------------------------------
// K3: fused GEMM: Wh = A @ Wcat (bf16, MFMA) -> writes
//     (a) WhB MFMA B-fragments (via per-wave LDS transpose),
//     (b) f1/f2 (from the 17th column-tile).
template <int KT>
__global__ __launch_bounds__(256) void k_gemm(const u16* __restrict__ A,
                                              const u16* __restrict__ Bp,
                                              u16* __restrict__ WhB,
                                              float* __restrict__ f1,
                                              float* __restrict__ f2) {
    constexpr int K = KT * 32;
    __shared__ __align__(16) u16 tile[4][2048];   // [wave][col2*16 + row]
    int tid = threadIdx.x;
    int w = tid >> 6, l = tid & 63;
    int gw = blockIdx.x * 4 + w;
    int rt = gw >> 1, colhalf = gw & 1;
    int m0 = rt << 4;
    int b = m0 >> 10, n0 = m0 & 1023;
    int jt = n0 >> 5, halfsel = (n0 >> 4) & 1;
    const bf16x8* Av = (const bf16x8*)A;
    const bf16x8* Bv = (const bf16x8*)Bp;
    int arow = m0 + (l & 15);
    bf16x8 af[KT];
    #pragma unroll
    for (int kt = 0; kt < KT; ++kt)
        af[kt] = Av[((size_t)arow * K + (kt << 5) + ((l >> 4) << 3)) >> 3];
    f32x4 acc[8];
    #pragma unroll
    for (int c = 0; c < 8; ++c) acc[c] = f32x4{0.f, 0.f, 0.f, 0.f};
    f32x4 acc16 = {0.f, 0.f, 0.f, 0.f};
    #pragma unroll
    for (int kt = 0; kt < KT; ++kt) {
        #pragma unroll
        for (int c = 0; c < 8; ++c) {
            int ct = (colhalf << 3) + c;
            acc[c] = __builtin_amdgcn_mfma_f32_16x16x32_bf16(
                af[kt], Bv[(kt * 17 + ct) * 64 + l], acc[c], 0, 0, 0);
        }
        if (colhalf == 0)
            acc16 = __builtin_amdgcn_mfma_f32_16x16x32_bf16(
                af[kt], Bv[(kt * 17 + 16) * 64 + l], acc16, 0, 0, 0);
    }
    int co = l & 15, ro = (l >> 4) << 2;
    if (colhalf == 0 && co < 8) {
        int h = co >> 1;
        float* fp = (co & 1) ? f2 : f1;
        int base = (((b << 2) + h) << 10) + n0 + ro;
        #pragma unroll
        for (int r = 0; r < 4; ++r) fp[base + r] = acc16[r];
    }
    u16* tw = tile[w];
    #pragma unroll
    for (int c = 0; c < 8; ++c) {
        int col2 = (c << 4) + co;
        u16x4 pk;
        #pragma unroll
        for (int r = 0; r < 4; ++r) pk[r] = f2b(acc[c][r]);
        *(u16x4*)(tw + (col2 << 4) + ro) = pk;
    }
    __syncthreads();
    int lp = (halfsel << 5) + (l & 31);
    #pragma unroll
    for (int c4 = 0; c4 < 4; ++c4) {
        int combo = (c4 << 1) + (l >> 5);
        int hh = combo >> 2, ft = combo & 3;
        int col2 = (hh << 6) + (ft << 4) + (l & 15);
        int r0 = ((l >> 4) & 1) << 3;
        bf16x8 v = *(const bf16x8*)(tw + (col2 << 4) + r0);
        int h = (colhalf << 1) + hh;
        int bh = (b << 2) + h;
        size_t fidx = (size_t)((bh << 7) + (jt << 2) + ft);
        *(bf16x8*)(WhB + (fidx * 64 + lp) * 8) = v;
    }
}

// ---------------------------------------------------------------------------
// K5: dense masked softmax + PV via MFMA, single pass.
// No max-subtraction (shift-invariant, magnitudes bounded); log2-domain exp;
// P packed via v_cvt_pk_bf16_f32; row sums via MFMA ones-column fragment.
template <int MODE>
__global__ __launch_bounds__(256) void k_pv(const u32* __restrict__ mask32,
                                            const float* __restrict__ f1g,
                                            const float* __restrict__ f2g,
                                            const bf16x8* __restrict__ Bv,
                                            u16* __restrict__ xout,
                                            float* __restrict__ out3) {
    __shared__ __align__(16) float f2s[1024];
    const float LOG2E = 1.44269504088896340736f;
    int tid = threadIdx.x;
    int w = tid >> 6, l = tid & 63;
    int bh = blockIdx.x >> 4;
    int b = bh >> 2, h = bh & 3;
    int itile = ((blockIdx.x & 15) << 2) + w;
    int i0 = itile << 4;
    for (int idx = tid; idx < 1024; idx += 256) f2s[idx] = f2g[(bh << 10) + idx] * LOG2E;
    __syncthreads();
    int row = l & 15;
    int g = l >> 4;
    int i = i0 + row;
    float f1i = f1g[(bh << 10) + i] * LOG2E;
    const u32x4* m4 = (const u32x4*)(mask32 + (((size_t)(b << 10) + i) << 5));
    u32 mw[32];
    #pragma unroll
    for (int t4 = 0; t4 < 8; ++t4) {
        u32x4 q = m4[t4];
        mw[t4 * 4 + 0] = q[0]; mw[t4 * 4 + 1] = q[1];
        mw[t4 * 4 + 2] = q[2]; mw[t4 * 4 + 3] = q[3];
    }
    u32 anyb = 0;
    #pragma unroll
    for (int jt = 0; jt < 32; ++jt) anyb |= mw[jt];
    float d0f = (anyb == 0u) ? 1.0f : 0.0f;   // deg==0 -> uniform softmax
    u32 onep = (row == 0) ? 0x3F803F80u : 0u; // ones in B-col 0 -> row sums
    u32x4 ov = {onep, onep, onep, onep};
    bf16x8 sfrag = __builtin_bit_cast(bf16x8, ov);
    f32x4 acc[4];
    #pragma unroll
    for (int ft = 0; ft < 4; ++ft) acc[ft] = f32x4{0.f, 0.f, 0.f, 0.f};
    f32x4 accs = {0.f, 0.f, 0.f, 0.f};
    const f32x4* f2v4 = (const f32x4*)f2s;
    int fragbase = bh << 7;
    for (int jt = 0; jt < 32; ++jt) {
        u32 sh = mw[jt] >> (g << 3);
        f32x4 fa = f2v4[(jt << 3) + (g << 1)];
        f32x4 fb = f2v4[(jt << 3) + (g << 1) + 1];
        float p[8];
        #pragma unroll
        for (int jj = 0; jj < 8; ++jj) {
            float f2j = (jj < 4) ? fa[jj] : fb[jj - 4];
            float t = f1i + f2j;
            float e = fmaxf(t, 0.2f * t);       // leakyrelu in log2 domain
            float ex;
#if __has_builtin(__builtin_amdgcn_exp2f)
            ex = __builtin_amdgcn_exp2f(e);
#else
            asm("v_exp_f32 %0, %1" : "=v"(ex) : "v"(e));
#endif
            p[jj] = (sh & (1u << jj)) ? ex : d0f;
        }
        u32x4 pk;
        #pragma unroll
        for (int q = 0; q < 4; ++q) {
            u32 r;
            asm("v_cvt_pk_bf16_f32 %0, %1, %2" : "=v"(r) : "v"(p[2 * q]), "v"(p[2 * q + 1]));
            pk[q] = r;
        }
        bf16x8 af = __builtin_bit_cast(bf16x8, pk);
        accs = __builtin_amdgcn_mfma_f32_16x16x32_bf16(af, sfrag, accs, 0, 0, 0);
        #pragma unroll
        for (int ft = 0; ft < 4; ++ft)
            acc[ft] = __builtin_amdgcn_mfma_f32_16x16x32_bf16(
                af, Bv[(size_t)(fragbase + (jt << 2) + ft) * 64 + l], acc[ft], 0, 0, 0);
    }
    #pragma unroll
    for (int reg = 0; reg < 4; ++reg) {
        int orow = (g << 2) + reg;
        float s = __shfl(accs[reg], g << 4, 64);   // C[row=orow][col 0]
        float rinv = 1.0f / s;
        int grow = i0 + orow;
        #pragma unroll
        for (int ft = 0; ft < 4; ++ft) {
            float v = acc[ft][reg] * rinv;
            if (MODE == 0) {
                float e2 = v > 0.0f ? v : (__expf(v) - 1.0f);   // elu
                xout[((size_t)((b << 10) + grow) << 8) + (h << 6) + (ft << 4) + row] = f2b(e2);
            } else {
                out3[((size_t)((bh << 10) + grow) << 6) + (ft << 4) + row] = v;
            }
        }
    }
}

// ---------------------------------------------------------------------------
// K6: final head-mean -> sigmoid -> dot(hidden) -> outputs
__global__ __launch_bounds__(64) void k_final(const float* __restrict__ out3,
                                              const float* __restrict__ hidden,
                                              float* __restrict__ dout) {
    int bn = blockIdx.x;
    int b = bn >> 10, n = bn & 1023;
    int f = threadIdx.x;
    float s = 0.0f;
    #pragma unroll
    for (int h = 0; h < 4; ++h)
        s += out3[((((size_t)(b * 4 + h) << 10) + n) << 6) + f];
    s *= 0.25f;
    float x = 1.0f / (1.0f + __expf(-s));
    float prod = x * hidden[(b << 6) + f];
    float logit = wred_sum(prod);
    if (f == 0) {
        dout[bn] = 1.0f / (1.0f + __expf(-logit));
        dout[17408 + bn] = logit;
    }
    if (n == 0) dout[16384 + (b << 6) + f] = hidden[(b << 6) + f];
}

// ---------------------------------------------------------------------------
extern "C" void kernel_launch(void* const* d_in, const int* in_sizes, int n_in,
                              void* d_out, int out_size, void* d_ws, size_t ws_size,
                              hipStream_t stream) {
    const int*   story  = (const int*)d_in[0];
    const int*   kb     = (const int*)d_in[1];
    const int*   cv     = (const int*)d_in[2];
    const float* hidden = (const float*)d_in[3];
    const float* dh     = (const float*)d_in[4];
    const float* adj    = (const float*)d_in[5];
    const float* emb    = (const float*)d_in[6];
    const float* W1     = (const float*)d_in[7];
    const float* a1     = (const float*)d_in[8];
    const float* W2     = (const float*)d_in[9];
    const float* a2     = (const float*)d_in[10];
    const float* W3     = (const float*)d_in[11];
    const float* a3     = (const float*)d_in[12];
    float* dout = (float*)d_out;

    char* ws = (char*)d_ws;
    u64*   mask   = (u64*)(ws + 0);               //  2 MB
    u32*   mask32 = (u32*)(ws + 0);               //  alias
    u16*   x0   = (u16*)(ws + 2097152);           //  4 MB
    u16*   xbf  = (u16*)(ws + 6291456);           //  8 MB
    u16*   WhB  = (u16*)(ws + 14680064);          //  8 MB packed B-fragments
    float* f1   = (float*)(ws + 23068672);        //  256 KB
    float* f2   = (float*)(ws + 23330816);        //  256 KB
    u16*   Bp   = (u16*)(ws + 23592960);          //  272 KB
    float* wa   = (float*)(ws + 23871488);        //  8 KB
    float* out3 = (float*)(ws + 23879680);        //  16 MB (end ~38.8 MB)

    k_mask<<<4096, 256, 0, stream>>>(adj, kb, cv, mask);
    k_x0<<<16384, 128, 0, stream>>>(story, kb, cv, dh, emb, x0);

    // ---- layer 1 (K=128) ----
    k_wa<<<4, 256, 0, stream>>>(W1, a1, wa, 127, 7);
    k_prepW<<<136, 256, 0, stream>>>(W1, wa, Bp, 128);
    k_gemm<4><<<512, 256, 0, stream>>>(x0, Bp, WhB, f1, f2);
    k_pv<0><<<1024, 256, 0, stream>>>(mask32, f1, f2, (const bf16x8*)WhB, xbf, nullptr);

    // ---- layer 2 (K=256) ----
    k_wa<<<8, 256, 0, stream>>>(W2, a2, wa, 255, 8);
    k_prepW<<<272, 256, 0, stream>>>(W2, wa, Bp, 256);
    k_gemm<8><<<512, 256, 0, stream>>>(xbf, Bp, WhB, f1, f2);
    k_pv<0><<<1024, 256, 0, stream>>>(mask32, f1, f2, (const bf16x8*)WhB, xbf, nullptr);

    // ---- layer 3 (K=256, mean over heads) ----
    k_wa<<<8, 256, 0, stream>>>(W3, a3, wa, 255, 8);
    k_prepW<<<272, 256, 0, stream>>>(W3, wa, Bp, 256);
    k_gemm<8><<<512, 256, 0, stream>>>(xbf, Bp, WhB, f1, f2);
    k_pv<1><<<1024, 256, 0, stream>>>(mask32, f1, f2, (const bf16x8*)WhB, nullptr, out3);

    k_final<<<16384, 64, 0, stream>>>(out3, hidden, dout);
}

// Round 5
// 163.856 us; speedup vs baseline: 14.6468x; 1.1155x over previous
//
#include <hip/hip_runtime.h>
#include <stdint.h>

typedef short bf16x8 __attribute__((ext_vector_type(8)));
typedef float f32x4 __attribute__((ext_vector_type(4)));
typedef unsigned short u16;
typedef unsigned short u16x4 __attribute__((ext_vector_type(4)));
typedef unsigned int u32;
typedef unsigned int u32x4 __attribute__((ext_vector_type(4)));
typedef unsigned long long u64;

// B=16, N=1024, T=6, V=32000, D=128, F=64, H=4, LC=400

__device__ inline u16 f2b(float f) {
    unsigned u = __float_as_uint(f);
    u += 0x7fffu + ((u >> 16) & 1u);
    return (u16)(u >> 16);
}

__device__ inline float wred_sum(float v) {
    #pragma unroll
    for (int m = 32; m >= 1; m >>= 1) v += __shfl_xor(v, m, 64);
    return v;
}

// ---------------------------------------------------------------------------
// K_pre: fused. Blocks [0,4096): adjacency -> bitmask with diagonal fix.
//        Blocks [4096,12288): x0 = sum_t emb[story] + (valid ? dh : 0) (bf16).
__global__ __launch_bounds__(256) void k_pre(const float* __restrict__ adj,
                                             const int* __restrict__ kb,
                                             const int* __restrict__ cv,
                                             const int* __restrict__ story,
                                             const float* __restrict__ dh,
                                             const float* __restrict__ emb,
                                             u64* __restrict__ mask,
                                             u16* __restrict__ x0) {
    int bid = blockIdx.x;
    int tid = threadIdx.x;
    if (bid < 4096) {
        int w = tid >> 6, l = tid & 63;
        int row = bid * 4 + w;               // b*1024 + i
        int b = row >> 10, i = row & 1023;
        int start = kb[b] + cv[b];
        const float* arow = adj + ((size_t)row << 10);
        u64* mrow = mask + ((size_t)row << 4);
        #pragma unroll
        for (int wd = 0; wd < 16; ++wd) {
            int j = (wd << 6) | l;
            bool p = arow[j] > 0.0f;
            if (j == i && i >= start) p = true;
            u64 bal = __ballot(p);
            if (l == 0) mrow[wd] = bal;
        }
    } else {
        int bn = ((bid - 4096) << 1) + (tid >> 7);
        int b = bn >> 10, n = bn & 1023;
        int d = tid & 127;
        const int* st = story + (size_t)bn * 6;
        float s = 0.0f;
        #pragma unroll
        for (int t = 0; t < 6; ++t) {
            int tok = st[t];
            s += emb[((size_t)tok << 7) + d];
        }
        int off = n - (kb[b] - 1);
        if (off >= 0 && off < cv[b]) s += dh[((size_t)b * 400 + off) * 128 + d];
        x0[((size_t)bn << 7) + d] = f2b(s);
    }
}

// ---------------------------------------------------------------------------
// K_wa_all: wa[c][k] = W[h][k][:] . a[h][half] for all 3 layers, one thread/dot.
__global__ __launch_bounds__(256) void k_wa_all(const float* __restrict__ W1,
                                                const float* __restrict__ a1,
                                                const float* __restrict__ W2,
                                                const float* __restrict__ a2,
                                                const float* __restrict__ W3,
                                                const float* __restrict__ a3,
                                                float* __restrict__ wa) {
    int bid = blockIdx.x;
    const float *W, *a; float* o; int Kmask, kshift;
    if (bid < 4)       { W = W1; a = a1; o = wa;        Kmask = 127; kshift = 7; }
    else if (bid < 12) { W = W2; a = a2; o = wa + 1024; Kmask = 255; kshift = 8; bid -= 4; }
    else               { W = W3; a = a3; o = wa + 3072; Kmask = 255; kshift = 8; bid -= 12; }
    int id = bid * 256 + threadIdx.x;
    int c = id >> kshift, k = id & Kmask;
    int h = c >> 1, wh = c & 1;
    const float4* wr = (const float4*)(W + ((size_t)(h << kshift) + k) * 64);
    const float4* av = (const float4*)(a + h * 128 + wh * 64);
    float s = 0.0f;
    #pragma unroll
    for (int q = 0; q < 16; ++q) {
        float4 x = wr[q], y = av[q];
        s += x.x * y.x + x.y * y.y + x.z * y.z + x.w * y.w;
    }
    o[id] = s;
}

// ---------------------------------------------------------------------------
// K_prepW_all: pack W -> MFMA B-fragments (17 column-tiles/kt) for all layers.
//   ct 0..15: Wcat columns. ct 16: cols 0..7 = wa vectors; cols 8..15 zero.
__global__ __launch_bounds__(256) void k_prepW_all(const float* __restrict__ W1,
                                                   const float* __restrict__ W2,
                                                   const float* __restrict__ W3,
                                                   const float* __restrict__ wa,
                                                   u16* __restrict__ Bp1,
                                                   u16* __restrict__ Bp2,
                                                   u16* __restrict__ Bp3) {
    int bid = blockIdx.x;
    const float* W; const float* wav; u16* Bp; int K;
    if (bid < 136)      { W = W1; wav = wa;        Bp = Bp1; K = 128; }
    else if (bid < 408) { W = W2; wav = wa + 1024; Bp = Bp2; K = 256; bid -= 136; }
    else                { W = W3; wav = wa + 3072; Bp = Bp3; K = 256; bid -= 408; }
    int id = bid * 256 + threadIdx.x;
    int j = id & 7, lane = (id >> 3) & 63, fr = id >> 9;
    int kt = fr / 17, ct = fr - kt * 17;
    int kk = (kt << 5) + ((lane >> 4) << 3) + j;
    u16 o;
    if (ct < 16) {
        int col = (ct << 4) | (lane & 15);
        o = f2b(W[((size_t)(col >> 6) * K + kk) * 64 + (col & 63)]);
    } else {
        int c = lane & 15;
        o = (c < 8) ? f2b(wav[c * K + kk]) : (u16)0;
    }
    Bp[id] = o;
}

// ---------------------------------------------------------------------------
// K_gemm: Wh = A @ Wcat (bf16, MFMA) -> WhB fragments (LDS transpose) + f1/f2.
template <int KT>
__global__ __launch_bounds__(256) void k_gemm(const u16* __restrict__ A,
                                              const u16* __restrict__ Bp,
                                              u16* __restrict__ WhB,
                                              float* __restrict__ f1,
                                              float* __restrict__ f2) {
    constexpr int K = KT * 32;
    __shared__ __align__(16) u16 tile[4][2048];   // [wave][col2*16 + row]
    int tid = threadIdx.x;
    int w = tid >> 6, l = tid & 63;
    int gw = blockIdx.x * 4 + w;
    int rt = gw >> 1, colhalf = gw & 1;
    int m0 = rt << 4;
    int b = m0 >> 10, n0 = m0 & 1023;
    int jt = n0 >> 5, halfsel = (n0 >> 4) & 1;
    const bf16x8* Av = (const bf16x8*)A;
    const bf16x8* Bv = (const bf16x8*)Bp;
    int arow = m0 + (l & 15);
    bf16x8 af[KT];
    #pragma unroll
    for (int kt = 0; kt < KT; ++kt)
        af[kt] = Av[((size_t)arow * K + (kt << 5) + ((l >> 4) << 3)) >> 3];
    f32x4 acc[8];
    #pragma unroll
    for (int c = 0; c < 8; ++c) acc[c] = f32x4{0.f, 0.f, 0.f, 0.f};
    f32x4 acc16 = {0.f, 0.f, 0.f, 0.f};
    #pragma unroll
    for (int kt = 0; kt < KT; ++kt) {
        #pragma unroll
        for (int c = 0; c < 8; ++c) {
            int ct = (colhalf << 3) + c;
            acc[c] = __builtin_amdgcn_mfma_f32_16x16x32_bf16(
                af[kt], Bv[(kt * 17 + ct) * 64 + l], acc[c], 0, 0, 0);
        }
        if (colhalf == 0)
            acc16 = __builtin_amdgcn_mfma_f32_16x16x32_bf16(
                af[kt], Bv[(kt * 17 + 16) * 64 + l], acc16, 0, 0, 0);
    }
    int co = l & 15, ro = (l >> 4) << 2;
    if (colhalf == 0 && co < 8) {
        int h = co >> 1;
        float* fp = (co & 1) ? f2 : f1;
        int base = (((b << 2) + h) << 10) + n0 + ro;
        #pragma unroll
        for (int r = 0; r < 4; ++r) fp[base + r] = acc16[r];
    }
    u16* tw = tile[w];
    #pragma unroll
    for (int c = 0; c < 8; ++c) {
        int col2 = (c << 4) + co;
        u16x4 pk;
        #pragma unroll
        for (int r = 0; r < 4; ++r) pk[r] = f2b(acc[c][r]);
        *(u16x4*)(tw + (col2 << 4) + ro) = pk;
    }
    __syncthreads();
    int lp = (halfsel << 5) + (l & 31);
    #pragma unroll
    for (int c4 = 0; c4 < 4; ++c4) {
        int combo = (c4 << 1) + (l >> 5);
        int hh = combo >> 2, ft = combo & 3;
        int col2 = (hh << 6) + (ft << 4) + (l & 15);
        int r0 = ((l >> 4) & 1) << 3;
        bf16x8 v = *(const bf16x8*)(tw + (col2 << 4) + r0);
        int h = (colhalf << 1) + hh;
        int bh = (b << 2) + h;
        size_t fidx = (size_t)((bh << 7) + (jt << 2) + ft);
        *(bf16x8*)(WhB + (fidx * 64 + lp) * 8) = v;
    }
}

// ---------------------------------------------------------------------------
// Shared PV core: P generated in registers (log2 domain, no max-shift),
// row sums via ones-column MFMA. Returns acc[4], accs.
#define PV_CORE(f2v4, mw, f1i, d0f, fragbase, Bv, acc, accs, g)                  \
    {                                                                            \
        u32 onep = ((l & 15) == 0) ? 0x3F803F80u : 0u;                           \
        u32x4 ov = {onep, onep, onep, onep};                                     \
        bf16x8 sfrag = __builtin_bit_cast(bf16x8, ov);                           \
        for (int jt = 0; jt < 32; ++jt) {                                        \
            u32 sh = mw[jt] >> (g << 3);                                         \
            f32x4 fa = f2v4[(jt << 3) + (g << 1)];                               \
            f32x4 fb = f2v4[(jt << 3) + (g << 1) + 1];                           \
            float p[8];                                                          \
            _Pragma("unroll")                                                    \
            for (int jj = 0; jj < 8; ++jj) {                                     \
                float f2j = (jj < 4) ? fa[jj] : fb[jj - 4];                      \
                float t = f1i + f2j;                                             \
                float e = fmaxf(t, 0.2f * t);                                    \
                float ex;                                                        \
                asm("v_exp_f32 %0, %1" : "=v"(ex) : "v"(e));                     \
                p[jj] = (sh & (1u << jj)) ? ex : d0f;                            \
            }                                                                    \
            u32x4 pk;                                                            \
            _Pragma("unroll")                                                    \
            for (int q = 0; q < 4; ++q) {                                        \
                u32 r;                                                           \
                asm("v_cvt_pk_bf16_f32 %0, %1, %2"                               \
                    : "=v"(r) : "v"(p[2 * q]), "v"(p[2 * q + 1]));               \
                pk[q] = r;                                                       \
            }                                                                    \
            bf16x8 af = __builtin_bit_cast(bf16x8, pk);                          \
            accs = __builtin_amdgcn_mfma_f32_16x16x32_bf16(af, sfrag, accs, 0, 0, 0); \
            _Pragma("unroll")                                                    \
            for (int ft = 0; ft < 4; ++ft)                                       \
                acc[ft] = __builtin_amdgcn_mfma_f32_16x16x32_bf16(               \
                    af, Bv[(size_t)(fragbase + (jt << 2) + ft) * 64 + l], acc[ft], 0, 0, 0); \
        }                                                                        \
    }

// ---------------------------------------------------------------------------
// K_pv0: concat layers. One wave = one 16-row i-tile of one (b,h).
__global__ __launch_bounds__(256) void k_pv0(const u32* __restrict__ mask32,
                                             const float* __restrict__ f1g,
                                             const float* __restrict__ f2g,
                                             const bf16x8* __restrict__ Bv,
                                             u16* __restrict__ xout) {
    __shared__ __align__(16) float f2s[1024];
    const float LOG2E = 1.44269504088896340736f;
    int tid = threadIdx.x;
    int w = tid >> 6, l = tid & 63;
    int bh = blockIdx.x >> 4;
    int b = bh >> 2, h = bh & 3;
    int itile = ((blockIdx.x & 15) << 2) + w;
    int i0 = itile << 4;
    for (int idx = tid; idx < 1024; idx += 256) f2s[idx] = f2g[(bh << 10) + idx] * LOG2E;
    __syncthreads();
    int row = l & 15, g = l >> 4;
    int i = i0 + row;
    float f1i = f1g[(bh << 10) + i] * LOG2E;
    const u32x4* m4 = (const u32x4*)(mask32 + (((size_t)(b << 10) + i) << 5));
    u32 mw[32];
    #pragma unroll
    for (int t4 = 0; t4 < 8; ++t4) {
        u32x4 q = m4[t4];
        mw[t4 * 4 + 0] = q[0]; mw[t4 * 4 + 1] = q[1];
        mw[t4 * 4 + 2] = q[2]; mw[t4 * 4 + 3] = q[3];
    }
    u32 anyb = 0;
    #pragma unroll
    for (int jt = 0; jt < 32; ++jt) anyb |= mw[jt];
    float d0f = (anyb == 0u) ? 1.0f : 0.0f;
    f32x4 acc[4];
    #pragma unroll
    for (int ft = 0; ft < 4; ++ft) acc[ft] = f32x4{0.f, 0.f, 0.f, 0.f};
    f32x4 accs = {0.f, 0.f, 0.f, 0.f};
    const f32x4* f2v4 = (const f32x4*)f2s;
    int fragbase = bh << 7;
    PV_CORE(f2v4, mw, f1i, d0f, fragbase, Bv, acc, accs, g)
    #pragma unroll
    for (int reg = 0; reg < 4; ++reg) {
        int orow = (g << 2) + reg;
        float s = __shfl(accs[reg], g << 4, 64);
        float rinv = 1.0f / s;
        int grow = i0 + orow;
        #pragma unroll
        for (int ft = 0; ft < 4; ++ft) {
            float v = acc[ft][reg] * rinv;
            float e2 = v > 0.0f ? v : (__expf(v) - 1.0f);   // elu
            xout[((size_t)((b << 10) + grow) << 8) + (h << 6) + (ft << 4) + row] = f2b(e2);
        }
    }
}

// ---------------------------------------------------------------------------
// K_pv3: final layer fused with head-mean/sigmoid/hidden-dot/final outputs.
// Block = (b, itile); wave w = head w. LDS reused: f2 staging -> head outputs.
__global__ __launch_bounds__(256) void k_pv3(const u32* __restrict__ mask32,
                                             const float* __restrict__ f1g,
                                             const float* __restrict__ f2g,
                                             const bf16x8* __restrict__ Bv,
                                             const float* __restrict__ hidden,
                                             float* __restrict__ dout) {
    __shared__ __align__(16) float shbuf[4096];   // [h][1024] f2 -> [h][row][f]
    const float LOG2E = 1.44269504088896340736f;
    int tid = threadIdx.x;
    int w = tid >> 6, l = tid & 63;
    int b = blockIdx.x >> 6;
    int itile = blockIdx.x & 63;
    int i0 = itile << 4;
    int bh = (b << 2) + w;
    for (int idx = tid; idx < 4096; idx += 256) shbuf[idx] = f2g[(b << 12) + idx] * LOG2E;
    __syncthreads();
    int row = l & 15, g = l >> 4;
    int i = i0 + row;
    float f1i = f1g[(bh << 10) + i] * LOG2E;
    const u32x4* m4 = (const u32x4*)(mask32 + (((size_t)(b << 10) + i) << 5));
    u32 mw[32];
    #pragma unroll
    for (int t4 = 0; t4 < 8; ++t4) {
        u32x4 q = m4[t4];
        mw[t4 * 4 + 0] = q[0]; mw[t4 * 4 + 1] = q[1];
        mw[t4 * 4 + 2] = q[2]; mw[t4 * 4 + 3] = q[3];
    }
    u32 anyb = 0;
    #pragma unroll
    for (int jt = 0; jt < 32; ++jt) anyb |= mw[jt];
    float d0f = (anyb == 0u) ? 1.0f : 0.0f;
    f32x4 acc[4];
    #pragma unroll
    for (int ft = 0; ft < 4; ++ft) acc[ft] = f32x4{0.f, 0.f, 0.f, 0.f};
    f32x4 accs = {0.f, 0.f, 0.f, 0.f};
    const f32x4* f2v4 = (const f32x4*)(shbuf + (w << 10));
    int fragbase = bh << 7;
    PV_CORE(f2v4, mw, f1i, d0f, fragbase, Bv, acc, accs, g)
    __syncthreads();   // all waves done reading f2 -> safe to reuse shbuf
    #pragma unroll
    for (int reg = 0; reg < 4; ++reg) {
        int orow = (g << 2) + reg;
        float s = __shfl(accs[reg], g << 4, 64);
        float rinv = 1.0f / s;
        #pragma unroll
        for (int ft = 0; ft < 4; ++ft)
            shbuf[(w << 10) + (orow << 6) + (ft << 4) + row] = acc[ft][reg] * rinv;
    }
    __syncthreads();
    float hid = hidden[(b << 6) + l];
    #pragma unroll
    for (int k = 0; k < 4; ++k) {
        int rl = (k << 2) + w;
        int o = (rl << 6) + l;
        float s = shbuf[o] + shbuf[1024 + o] + shbuf[2048 + o] + shbuf[3072 + o];
        s *= 0.25f;
        float x = 1.0f / (1.0f + __expf(-s));
        float logit = wred_sum(x * hid);
        if (l == 0) {
            int grow = i0 + rl;
            dout[(b << 10) + grow] = 1.0f / (1.0f + __expf(-logit));
            dout[17408 + (b << 10) + grow] = logit;
        }
    }
    if (itile == 0 && w == 0) dout[16384 + (b << 6) + l] = hid;
}

// ---------------------------------------------------------------------------
extern "C" void kernel_launch(void* const* d_in, const int* in_sizes, int n_in,
                              void* d_out, int out_size, void* d_ws, size_t ws_size,
                              hipStream_t stream) {
    const int*   story  = (const int*)d_in[0];
    const int*   kb     = (const int*)d_in[1];
    const int*   cv     = (const int*)d_in[2];
    const float* hidden = (const float*)d_in[3];
    const float* dh     = (const float*)d_in[4];
    const float* adj    = (const float*)d_in[5];
    const float* emb    = (const float*)d_in[6];
    const float* W1     = (const float*)d_in[7];
    const float* a1     = (const float*)d_in[8];
    const float* W2     = (const float*)d_in[9];
    const float* a2     = (const float*)d_in[10];
    const float* W3     = (const float*)d_in[11];
    const float* a3     = (const float*)d_in[12];
    float* dout = (float*)d_out;

    char* ws = (char*)d_ws;
    u64*   mask   = (u64*)(ws + 0);               //  2 MB
    u32*   mask32 = (u32*)(ws + 0);               //  alias
    u16*   x0   = (u16*)(ws + 2097152);           //  4 MB
    u16*   xbf  = (u16*)(ws + 6291456);           //  8 MB
    u16*   WhB  = (u16*)(ws + 14680064);          //  8 MB packed B-fragments
    float* f1   = (float*)(ws + 23068672);        //  256 KB
    float* f2   = (float*)(ws + 23330816);        //  256 KB
    u16*   Bp1  = (u16*)(ws + 23592960);          //  68 KB (K=128)
    u16*   Bp2  = (u16*)(ws + 23724032);          //  136 KB (K=256)
    u16*   Bp3  = (u16*)(ws + 23863296);          //  136 KB
    float* wa   = (float*)(ws + 24002560);        //  20 KB (end ~24 MB)

    k_wa_all<<<20, 256, 0, stream>>>(W1, a1, W2, a2, W3, a3, wa);
    k_prepW_all<<<680, 256, 0, stream>>>(W1, W2, W3, wa, Bp1, Bp2, Bp3);
    k_pre<<<12288, 256, 0, stream>>>(adj, kb, cv, story, dh, emb, mask, x0);

    // ---- layer 1 (K=128) ----
    k_gemm<4><<<512, 256, 0, stream>>>(x0, Bp1, WhB, f1, f2);
    k_pv0<<<1024, 256, 0, stream>>>(mask32, f1, f2, (const bf16x8*)WhB, xbf);

    // ---- layer 2 (K=256) ----
    k_gemm<8><<<512, 256, 0, stream>>>(xbf, Bp2, WhB, f1, f2);
    k_pv0<<<1024, 256, 0, stream>>>(mask32, f1, f2, (const bf16x8*)WhB, xbf);

    // ---- layer 3 (K=256, fused mean/sigmoid/dot epilogue) ----
    k_gemm<8><<<512, 256, 0, stream>>>(xbf, Bp3, WhB, f1, f2);
    k_pv3<<<1024, 256, 0, stream>>>(mask32, f1, f2, (const bf16x8*)WhB, hidden, dout);
}